// Round 7
// baseline (672.976 us; speedup 1.0000x reference)
//
#include <hip/hip_runtime.h>
#include <hip/hip_bf16.h>

// GCN_large R10: R9 layout (2 blocks/CU, 80384B LDS) + register dieting to
// kill the spill R9's counters exposed (WRITE_SIZE 336MB = scratch traffic).
// proj is split into two 2-m-tile passes (acc live 32 regs, not 64);
// exch_build decomposed per-m (frags 8m..8m+7 depend only on tile m).
// W B-frags are re-loaded once per proj (L2-hit) -- cheap vs spill.
// Peak demand ~112 unified regs < 128 cap of __launch_bounds__(512,4).
// Everything else byte-identical to R9 (verified green):
//   aB [112][256] XOR-swizzle (col ^ ((row&7)<<3)), mid-phase WAR barrier,
//   Xs [96][120] + X rows 96..111 in Xr3 regs, clamp trick for m=3/n=3,
//   xchg32 exchange path, swizzled epilogue.

#define NODE 112
#define NBATCH 4096
#define SXS 120                          // Xs stride (shorts)
#define AB_OFF (96*SXS)                  // 11520 shorts
#define SMEM_BYTES ((AB_OFF + 112*256)*2)   // 80384 B

typedef float  f4v   __attribute__((ext_vector_type(4)));
typedef float  f16v  __attribute__((ext_vector_type(16)));
typedef __bf16 bf8v  __attribute__((ext_vector_type(8)));
typedef short  s8v   __attribute__((ext_vector_type(8)));
typedef unsigned u4v __attribute__((ext_vector_type(4)));
typedef unsigned short ushort_t;

__device__ __forceinline__ ushort_t f2bf(float f) {
  union { float f; unsigned u; } v; v.f = f;
  unsigned r = v.u + 0x7FFFu + ((v.u >> 16) & 1u);   // RNE
  return (ushort_t)(r >> 16);
}
__device__ __forceinline__ float bf2f(ushort_t h) {
  union { unsigned u; float f; } v; v.u = ((unsigned)h) << 16; return v.f;
}
__device__ __forceinline__ unsigned pk2(float a, float b) {
  unsigned short ul = __builtin_bit_cast(unsigned short, (__bf16)a);
  unsigned short uh = __builtin_bit_cast(unsigned short, (__bf16)b);
  return (unsigned)ul | ((unsigned)uh << 16);
}
__device__ __forceinline__ bf8v ld_frag(const ushort_t* p) {
  s8v t = *(const s8v*)p;
  return __builtin_bit_cast(bf8v, t);
}
// exchange with lane^32 partner (verified R7-R9)
__device__ __forceinline__ unsigned xchg32(unsigned v, int lane) {
  return (unsigned)__builtin_amdgcn_ds_bpermute(((lane ^ 32) << 2), (int)v);
}
#define MFMA32(a,b,c) __builtin_amdgcn_mfma_f32_32x32x16_bf16((a),(b),(c),0,0,0)

// Per-m-tile piece of the verified exch_build: consumes ONE proj acc tile,
// emits fr[8M..8M+7] (8M..8M+3 for M==3). Logic byte-identical per-m.
template<int M>
__device__ __forceinline__ void exch_m(const f16v& acc, float bv, int lane,
                                       unsigned* fr)
{
  const bool hiH = (lane >> 5) != 0;
  unsigned P[4][2];
  const int NQ = (M==3) ? 2 : 4;          // skip nodes 112..127
  #pragma unroll
  for (int q=0;q<4;q++) {
    if (q >= NQ) break;
    float v0 = fmaxf(acc[4*q+0]+bv, 0.f);
    float v1 = fmaxf(acc[4*q+1]+bv, 0.f);
    float v2 = fmaxf(acc[4*q+2]+bv, 0.f);
    float v3 = fmaxf(acc[4*q+3]+bv, 0.f);
    P[q][0] = pk2(v0, v1);
    P[q][1] = pk2(v2, v3);
  }
  {
    unsigned s0 = hiH ? P[0][0] : P[1][0];
    unsigned s1 = hiH ? P[0][1] : P[1][1];
    unsigned r0 = xchg32(s0, lane);
    unsigned r1 = xchg32(s1, lane);
    unsigned o0 = hiH ? P[1][0] : P[0][0];
    unsigned o1 = hiH ? P[1][1] : P[0][1];
    fr[8*M+0] = hiH ? r0 : o0;
    fr[8*M+1] = hiH ? r1 : o1;
    fr[8*M+2] = hiH ? o0 : r0;
    fr[8*M+3] = hiH ? o1 : r1;
  }
  if (M < 3) {
    unsigned s0 = hiH ? P[2][0] : P[3][0];
    unsigned s1 = hiH ? P[2][1] : P[3][1];
    unsigned r0 = xchg32(s0, lane);
    unsigned r1 = xchg32(s1, lane);
    unsigned o0 = hiH ? P[3][0] : P[2][0];
    unsigned o1 = hiH ? P[3][1] : P[2][1];
    fr[8*M+4] = hiH ? r0 : o0;
    fr[8*M+5] = hiH ? r1 : o1;
    fr[8*M+6] = hiH ? o0 : r0;
    fr[8*M+7] = hiH ? o1 : r1;
  }
}

// phase-1 proj pass (2 m-tiles): A from Xs (rows l31/32+l31 or 64+l31/Xr3).
template<int M0>
__device__ __forceinline__ void proj1_pass(
    const ushort_t* Xs, const bf8v* Xr3, const ushort_t* __restrict__ Wg,
    const float* __restrict__ bias, int nt, int lane, unsigned* fr)
{
  const int l31 = lane & 31, h32 = lane >> 5;
  f16v acc0, acc1;
  #pragma unroll
  for (int r=0;r<16;r++) { acc0[r] = 0.f; acc1[r] = 0.f; }

  const ushort_t* aP0 = Xs + ((M0==0 ? 0 : 64) + l31)*SXS + h32*8;
  const ushort_t* aP1 = Xs + (32 + l31)*SXS + h32*8;   // used when M0==0
  const ushort_t* bP  = Wg + (nt*32 + l31)*112 + h32*8;
  #pragma unroll
  for (int ks=0; ks<7; ks++) {
    bf8v B = ld_frag(bP + ks*16);
    acc0 = MFMA32(ld_frag(aP0 + ks*16), B, acc0);
    bf8v A1 = (M0==0) ? ld_frag(aP1 + ks*16) : Xr3[ks];
    acc1 = MFMA32(A1, B, acc1);
  }
  const float bv = bias[nt*32 + l31];
  exch_m<M0>(acc0, bv, lane, fr);
  exch_m<M0+1>(acc1, bv, lane, fr);
}

// phases 2-4 proj pass (2 m-tiles): A = aB (swizzled), B = W (global).
// M0==2 second tile clamped to rows 96+(l31&15) (feeds discarded D rows).
template<int KS, int M0>
__device__ __forceinline__ void proj_pass(
    const ushort_t* aBs, const ushort_t* __restrict__ Wg, int WK,
    const float* __restrict__ bias, int nt, int lane, int sw, unsigned* fr)
{
  const int l31 = lane & 31, h32 = lane >> 5;
  f16v acc0, acc1;
  #pragma unroll
  for (int r=0;r<16;r++) { acc0[r] = 0.f; acc1[r] = 0.f; }

  const int r0 = ((M0==0 ? 0 : 64) + l31)*256;
  const int r1 = (M0==0) ? (32 + l31)*256 : (96 + (l31 & 15))*256;
  const ushort_t* bP = Wg + (nt*32 + l31)*WK + h32*8;
  #pragma unroll
  for (int ks=0; ks<KS; ks++) {
    bf8v B = ld_frag(bP + ks*16);
    const int c = (16*ks + 8*h32) ^ sw;
    acc0 = MFMA32(ld_frag(aBs + r0 + c), B, acc0);
    acc1 = MFMA32(ld_frag(aBs + r1 + c), B, acc1);
  }
  const float bv = bias[nt*32 + l31];
  exch_m<M0>(acc0, bv, lane, fr);
  exch_m<M0+1>(acc1, bv, lane, fr);
}

// agg half: n-tiles {N0, N0+1}. A = fr (regs), B = Xs rows / Xr3 (n=3).
// Writes aB swizzled; n=3 masked to l31<16.
template<int N0>
__device__ __forceinline__ void agg_half(
    const unsigned* fr, const ushort_t* Xs, const bf8v* Xr3,
    ushort_t* aBs, int mt, int lane, int sw)
{
  const int l31 = lane & 31, h32 = lane >> 5;
  f16v acc0, acc1;
  #pragma unroll
  for (int r=0;r<16;r++) { acc0[r] = 0.f; acc1[r] = 0.f; }

  const ushort_t* bP = Xs + l31*SXS + h32*8;
  #pragma unroll
  for (int ks=0; ks<7; ks++) {              // K = 112 exact
    u4v t = (u4v){fr[4*ks+0], fr[4*ks+1], fr[4*ks+2], fr[4*ks+3]};
    bf8v A = __builtin_bit_cast(bf8v, t);
    bf8v B0 = ld_frag(bP + N0*32*SXS + ks*16);
    bf8v B1 = (N0 == 0) ? ld_frag(bP + 32*SXS + ks*16) : Xr3[ks];
    acc0 = MFMA32(A, B0, acc0);
    acc1 = MFMA32(A, B1, acc1);
  }

  #pragma unroll
  for (int s=0;s<2;s++) {
    const f16v& a = s ? acc1 : acc0;
    const int n = N0 + s;
    const int row = (n < 3) ? (n*32 + l31) : (96 + l31);
    const bool on = (n < 3) || (l31 < 16);
    #pragma unroll
    for (int q=0;q<4;q++) {
      uint2 pv;
      pv.x = pk2(a[4*q+0], a[4*q+1]);
      pv.y = pk2(a[4*q+2], a[4*q+3]);
      const int col = (mt*32 + 8*q + 4*h32) ^ sw;
      if (on) *(uint2*)(aBs + row*256 + col) = pv;
    }
  }
}

// weights, bf16: W1 [256][112] @0, W2 [256][256] @28672,
// W3 [128][256] @94208, W4 [64][128] @126976. total 135168 elems.
__global__ void prep_weights(const float* __restrict__ W1, const float* __restrict__ W2,
                             const float* __restrict__ W3, const float* __restrict__ W4,
                             ushort_t* __restrict__ o)
{
  int i = blockIdx.x*256 + threadIdx.x;
  if (i < 28672)       o[i] = f2bf(W1[i]);
  else if (i < 94208)  o[i] = f2bf(W2[i - 28672]);
  else if (i < 126976) o[i] = f2bf(W3[i - 94208]);
  else if (i < 135168) o[i] = f2bf(W4[i - 126976]);
}

__global__ void __launch_bounds__(512, 4) gcn_kernel(
    const float* __restrict__ x, const ushort_t* __restrict__ wsp,
    const float* __restrict__ b1, const float* __restrict__ b2,
    const float* __restrict__ b3, const float* __restrict__ b4,
    const float* __restrict__ W5, const float* __restrict__ b5,
    const float* __restrict__ Wf, const float* __restrict__ bfc,
    float* __restrict__ out)
{
  extern __shared__ ushort_t smem[];
  ushort_t* Xs = smem;                 // [96][120]
  ushort_t* aB = smem + AB_OFF;        // [112][256] swizzled

  const int tid  = threadIdx.x;
  const int w    = tid >> 6;
  const int lane = tid & 63;
  const int l31  = lane & 31, h32 = lane >> 5;
  const int sw   = (l31 & 7) << 3;     // aB swizzle (per-lane constant)

  // stage X: rows 0..95 -> Xs; rows 96..111 -> linear strip at aB start
  {
    const float4* x4 = (const float4*)(x + (size_t)blockIdx.x * (NODE*NODE));
    for (int i = tid; i < (NODE*NODE/4); i += 512) {
      float4 v = x4[i];
      int r = i / 28, c4 = (i - r*28) * 4;
      uint2 pv; pv.x = pk2(v.x, v.y); pv.y = pk2(v.z, v.w);
      ushort_t* dst = (r < 96) ? (Xs + r*SXS + c4) : (aB + (r-96)*SXS + c4);
      *(uint2*)dst = pv;
    }
  }
  __syncthreads();

  // X rows 96..111 -> registers (lane's clamped row), then free the strip
  bf8v Xr3[7];
  {
    const ushort_t* sp = aB + (l31 & 15)*SXS + h32*8;
    #pragma unroll
    for (int ks=0;ks<7;ks++) Xr3[ks] = ld_frag(sp + ks*16);
  }
  __syncthreads();

  unsigned fr[28];

  // phase 1: proj from Xs/Xr3 (no aB read) -> fr -> agg writes aB
  proj1_pass<0>(Xs, Xr3, wsp, b1, w, lane, fr);
  proj1_pass<2>(Xs, Xr3, wsp, b1, w, lane, fr);
  agg_half<0>(fr, Xs, Xr3, aB, w, lane, sw);
  agg_half<2>(fr, Xs, Xr3, aB, w, lane, sw);
  __syncthreads();

  // phase 2: F=256, K=256
  proj_pass<16,0>(aB, wsp + 28672, 256, b2, w, lane, sw, fr);
  proj_pass<16,2>(aB, wsp + 28672, 256, b2, w, lane, sw, fr);
  __syncthreads();                     // all proj reads done before writes
  agg_half<0>(fr, Xs, Xr3, aB, w, lane, sw);
  agg_half<2>(fr, Xs, Xr3, aB, w, lane, sw);
  __syncthreads();

  // phase 3: F=128, K=256; waves 0..3
  if (w < 4) {
    proj_pass<16,0>(aB, wsp + 94208, 256, b3, w, lane, sw, fr);
    proj_pass<16,2>(aB, wsp + 94208, 256, b3, w, lane, sw, fr);
  }
  __syncthreads();
  if (w < 4) {
    agg_half<0>(fr, Xs, Xr3, aB, w, lane, sw);
    agg_half<2>(fr, Xs, Xr3, aB, w, lane, sw);
  }
  __syncthreads();

  // phase 4: F=64, K=128; waves 0..1
  if (w < 2) {
    proj_pass<8,0>(aB, wsp + 126976, 128, b4, w, lane, sw, fr);
    proj_pass<8,2>(aB, wsp + 126976, 128, b4, w, lane, sw, fr);
  }
  __syncthreads();
  if (w < 2) {
    agg_half<0>(fr, Xs, Xr3, aB, w, lane, sw);
    agg_half<2>(fr, Xs, Xr3, aB, w, lane, sw);
  }
  __syncthreads();

  // final: h5[n] = relu(b5 + a5[n][:].W5); out = bf + sum_n h5[n]*Wf[n]
  float partial = 0.f;
  if (tid < NODE) {
    const int swr = (tid & 7) << 3;
    const ushort_t* row = aB + tid*256;
    float s = 0.f;
    #pragma unroll
    for (int k4 = 0; k4 < 16; k4++) {
      uint2 u = *(const uint2*)(row + ((4*k4) ^ swr));
      s += bf2f((ushort_t)(u.x & 0xFFFF)) * W5[k4*4+0];
      s += bf2f((ushort_t)(u.x >> 16))    * W5[k4*4+1];
      s += bf2f((ushort_t)(u.y & 0xFFFF)) * W5[k4*4+2];
      s += bf2f((ushort_t)(u.y >> 16))    * W5[k4*4+3];
    }
    s += b5[0];
    s = s > 0.f ? s : 0.f;
    partial = s * Wf[tid];
  }
  float* red = (float*)Xs;             // Xs dead after phase 4
  if (tid < 128) red[tid] = partial;   // lanes 112..127 write 0
  __syncthreads();
  if (w == 0) {
    float v = red[lane] + red[lane + 64];
    #pragma unroll
    for (int off = 32; off > 0; off >>= 1)
      v += __shfl_xor(v, off, 64);
    if (lane == 0) out[blockIdx.x] = v + bfc[0];
  }
}

extern "C" void kernel_launch(void* const* d_in, const int* in_sizes, int n_in,
                              void* d_out, int out_size, void* d_ws, size_t ws_size,
                              hipStream_t stream) {
  const float* x   = (const float*)d_in[0];
  const float* W1  = (const float*)d_in[1];
  const float* b1  = (const float*)d_in[2];
  const float* W2  = (const float*)d_in[3];
  const float* b2  = (const float*)d_in[4];
  const float* W3  = (const float*)d_in[5];
  const float* b3  = (const float*)d_in[6];
  const float* W4  = (const float*)d_in[7];
  const float* b4  = (const float*)d_in[8];
  const float* W5  = (const float*)d_in[9];
  const float* b5  = (const float*)d_in[10];
  const float* Wf  = (const float*)d_in[11];
  const float* bfc = (const float*)d_in[12];
  ushort_t* wsp = (ushort_t*)d_ws;
  float* out = (float*)d_out;

  prep_weights<<<528, 256, 0, stream>>>(W1, W2, W3, W4, wsp);

  (void)hipFuncSetAttribute((const void*)gcn_kernel,
                            hipFuncAttributeMaxDynamicSharedMemorySize, SMEM_BYTES);
  gcn_kernel<<<NBATCH, 512, SMEM_BYTES, stream>>>(x, wsp, b1, b2, b3, b4,
                                                  W5, b5, Wf, bfc, out);
}

// Round 8
// 534.315 us; speedup vs baseline: 1.2595x; 1.2595x over previous
//
#include <hip/hip_runtime.h>
#include <hip/hip_bf16.h>

// GCN_large R11: 256-thread / 4-wave blocks, one batch item each.
// R10's counters proved the 128-reg cap of (512thr, 2 blk/CU) force-spills
// fr[28]+Xr3[7] (250 B/thread scratch -> 960MB HBM traffic). Fix: 4-wave
// blocks. 2 blocks/CU by LDS (2x80384B <= 160KiB) = 8 waves/CU, and at
// 8 waves/CU the reg budget is 256/wave -> no spill (demand ~190).
// Gains vs R8 (same 8 waves/CU): independent barrier domains between the
// two co-resident blocks + better tail-phase wave util (p1/p2: 2 tiles
// per wave seq; p3: ALL 4 waves; p4: 2 of 4).
// All math byte-identical to verified R9: aB [112][256] XOR-swizzle
// (col ^ ((row&7)<<3)), Xs [96][120] + X rows 96..111 in Xr3 regs,
// clamp trick m=3/n=3, xchg32 exchange, mid-phase WAR barrier in p2-p4.

#define NODE 112
#define NBATCH 4096
#define SXS 120                          // Xs stride (shorts)
#define AB_OFF (96*SXS)                  // 11520 shorts
#define SMEM_BYTES ((AB_OFF + 112*256)*2)   // 80384 B

typedef float  f4v   __attribute__((ext_vector_type(4)));
typedef float  f16v  __attribute__((ext_vector_type(16)));
typedef __bf16 bf8v  __attribute__((ext_vector_type(8)));
typedef short  s8v   __attribute__((ext_vector_type(8)));
typedef unsigned u4v __attribute__((ext_vector_type(4)));
typedef unsigned short ushort_t;

__device__ __forceinline__ ushort_t f2bf(float f) {
  union { float f; unsigned u; } v; v.f = f;
  unsigned r = v.u + 0x7FFFu + ((v.u >> 16) & 1u);   // RNE
  return (ushort_t)(r >> 16);
}
__device__ __forceinline__ float bf2f(ushort_t h) {
  union { unsigned u; float f; } v; v.u = ((unsigned)h) << 16; return v.f;
}
__device__ __forceinline__ unsigned pk2(float a, float b) {
  unsigned short ul = __builtin_bit_cast(unsigned short, (__bf16)a);
  unsigned short uh = __builtin_bit_cast(unsigned short, (__bf16)b);
  return (unsigned)ul | ((unsigned)uh << 16);
}
__device__ __forceinline__ bf8v ld_frag(const ushort_t* p) {
  s8v t = *(const s8v*)p;
  return __builtin_bit_cast(bf8v, t);
}
// exchange with lane^32 partner (verified R7-R10)
__device__ __forceinline__ unsigned xchg32(unsigned v, int lane) {
  return (unsigned)__builtin_amdgcn_ds_bpermute(((lane ^ 32) << 2), (int)v);
}
#define MFMA32(a,b,c) __builtin_amdgcn_mfma_f32_32x32x16_bf16((a),(b),(c),0,0,0)

// Build agg-A fragments fr[28] from proj accumulators (+bias, relu).
// Byte-identical to the verified R7/R9 epilogue.
__device__ __forceinline__ void exch_build(const f16v* acc, float bv, int lane,
                                           unsigned* fr)
{
  const bool hiH = (lane >> 5) != 0;
  #pragma unroll
  for (int m=0;m<4;m++) {
    unsigned P[4][2];
    const int NQ = (m==3) ? 2 : 4;          // skip nodes 112..127
    #pragma unroll
    for (int q=0;q<4;q++) {
      if (q >= NQ) break;
      float v0 = fmaxf(acc[m][4*q+0]+bv, 0.f);
      float v1 = fmaxf(acc[m][4*q+1]+bv, 0.f);
      float v2 = fmaxf(acc[m][4*q+2]+bv, 0.f);
      float v3 = fmaxf(acc[m][4*q+3]+bv, 0.f);
      P[q][0] = pk2(v0, v1);
      P[q][1] = pk2(v2, v3);
    }
    {
      unsigned s0 = hiH ? P[0][0] : P[1][0];
      unsigned s1 = hiH ? P[0][1] : P[1][1];
      unsigned r0 = xchg32(s0, lane);
      unsigned r1 = xchg32(s1, lane);
      unsigned o0 = hiH ? P[1][0] : P[0][0];
      unsigned o1 = hiH ? P[1][1] : P[0][1];
      fr[8*m+0] = hiH ? r0 : o0;
      fr[8*m+1] = hiH ? r1 : o1;
      fr[8*m+2] = hiH ? o0 : r0;
      fr[8*m+3] = hiH ? o1 : r1;
    }
    if (m < 3) {
      unsigned s0 = hiH ? P[2][0] : P[3][0];
      unsigned s1 = hiH ? P[2][1] : P[3][1];
      unsigned r0 = xchg32(s0, lane);
      unsigned r1 = xchg32(s1, lane);
      unsigned o0 = hiH ? P[3][0] : P[2][0];
      unsigned o1 = hiH ? P[3][1] : P[2][1];
      fr[8*m+4] = hiH ? r0 : o0;
      fr[8*m+5] = hiH ? r1 : o1;
      fr[8*m+6] = hiH ? o0 : r0;
      fr[8*m+7] = hiH ? o1 : r1;
    }
  }
}

// phase-1 proj: A rows 0..95 from Xs, rows 96.. from Xr3. K = 112 exact.
__device__ __forceinline__ void proj1_exch(
    const ushort_t* Xs, const bf8v* Xr3, const ushort_t* __restrict__ Wg,
    const float* __restrict__ bias, int nt, int lane, unsigned* fr)
{
  const int l31 = lane & 31, h32 = lane >> 5;
  f16v acc[4];
  #pragma unroll
  for (int m=0;m<4;m++)
    #pragma unroll
    for (int r=0;r<16;r++) acc[m][r] = 0.f;

  const ushort_t* aP = Xs + l31*SXS + h32*8;
  const ushort_t* bP = Wg + (nt*32 + l31)*112 + h32*8;
  #pragma unroll
  for (int ks=0; ks<7; ks++) {
    bf8v B = ld_frag(bP + ks*16);
    acc[0] = MFMA32(ld_frag(aP +          ks*16), B, acc[0]);
    acc[1] = MFMA32(ld_frag(aP + 32*SXS + ks*16), B, acc[1]);
    acc[2] = MFMA32(ld_frag(aP + 64*SXS + ks*16), B, acc[2]);
    acc[3] = MFMA32(Xr3[ks], B, acc[3]);
  }
  exch_build(acc, bias[nt*32 + l31], lane, fr);
}

// phases 2-4 proj: A = aB (swizzled), B = W (global, stride WK).
// m=3 rows clamped to 96+(l31&15) (duplicates feed discarded D rows).
template<int KS>
__device__ __forceinline__ void proj_exch(
    const ushort_t* aBs, const ushort_t* __restrict__ Wg, int WK,
    const float* __restrict__ bias, int nt, int lane, int sw, unsigned* fr)
{
  const int l31 = lane & 31, h32 = lane >> 5;
  f16v acc[4];
  #pragma unroll
  for (int m=0;m<4;m++)
    #pragma unroll
    for (int r=0;r<16;r++) acc[m][r] = 0.f;

  const int r0 = l31*256, r1 = (32+l31)*256, r2 = (64+l31)*256;
  const int r3 = (96 + (l31 & 15))*256;
  const ushort_t* bP = Wg + (nt*32 + l31)*WK + h32*8;
  #pragma unroll
  for (int ks=0; ks<KS; ks++) {
    bf8v B = ld_frag(bP + ks*16);
    const int c = (16*ks + 8*h32) ^ sw;
    acc[0] = MFMA32(ld_frag(aBs + r0 + c), B, acc[0]);
    acc[1] = MFMA32(ld_frag(aBs + r1 + c), B, acc[1]);
    acc[2] = MFMA32(ld_frag(aBs + r2 + c), B, acc[2]);
    acc[3] = MFMA32(ld_frag(aBs + r3 + c), B, acc[3]);
  }
  exch_build(acc, bias[nt*32 + l31], lane, fr);
}

// agg half: n-tiles {N0, N0+1}. A = fr (regs), B = Xs rows / Xr3 (n=3).
// Writes aB swizzled; n=3 masked to l31<16.
template<int N0>
__device__ __forceinline__ void agg_half(
    const unsigned* fr, const ushort_t* Xs, const bf8v* Xr3,
    ushort_t* aBs, int mt, int lane, int sw)
{
  const int l31 = lane & 31, h32 = lane >> 5;
  f16v acc0, acc1;
  #pragma unroll
  for (int r=0;r<16;r++) { acc0[r] = 0.f; acc1[r] = 0.f; }

  const ushort_t* bP = Xs + l31*SXS + h32*8;
  #pragma unroll
  for (int ks=0; ks<7; ks++) {              // K = 112 exact
    u4v t = (u4v){fr[4*ks+0], fr[4*ks+1], fr[4*ks+2], fr[4*ks+3]};
    bf8v A = __builtin_bit_cast(bf8v, t);
    bf8v B0 = ld_frag(bP + N0*32*SXS + ks*16);
    bf8v B1 = (N0 == 0) ? ld_frag(bP + 32*SXS + ks*16) : Xr3[ks];
    acc0 = MFMA32(A, B0, acc0);
    acc1 = MFMA32(A, B1, acc1);
  }

  #pragma unroll
  for (int s=0;s<2;s++) {
    const f16v& a = s ? acc1 : acc0;
    const int n = N0 + s;
    const int row = (n < 3) ? (n*32 + l31) : (96 + l31);
    const bool on = (n < 3) || (l31 < 16);
    #pragma unroll
    for (int q=0;q<4;q++) {
      uint2 pv;
      pv.x = pk2(a[4*q+0], a[4*q+1]);
      pv.y = pk2(a[4*q+2], a[4*q+3]);
      const int col = (mt*32 + 8*q + 4*h32) ^ sw;
      if (on) *(uint2*)(aBs + row*256 + col) = pv;
    }
  }
}

// weights, bf16: W1 [256][112] @0, W2 [256][256] @28672,
// W3 [128][256] @94208, W4 [64][128] @126976. total 135168 elems.
__global__ void prep_weights(const float* __restrict__ W1, const float* __restrict__ W2,
                             const float* __restrict__ W3, const float* __restrict__ W4,
                             ushort_t* __restrict__ o)
{
  int i = blockIdx.x*256 + threadIdx.x;
  if (i < 28672)       o[i] = f2bf(W1[i]);
  else if (i < 94208)  o[i] = f2bf(W2[i - 28672]);
  else if (i < 126976) o[i] = f2bf(W3[i - 94208]);
  else if (i < 135168) o[i] = f2bf(W4[i - 126976]);
}

__global__ void __launch_bounds__(256, 2) gcn_kernel(
    const float* __restrict__ x, const ushort_t* __restrict__ wsp,
    const float* __restrict__ b1, const float* __restrict__ b2,
    const float* __restrict__ b3, const float* __restrict__ b4,
    const float* __restrict__ W5, const float* __restrict__ b5,
    const float* __restrict__ Wf, const float* __restrict__ bfc,
    float* __restrict__ out)
{
  extern __shared__ ushort_t smem[];
  ushort_t* Xs = smem;                 // [96][120]
  ushort_t* aB = smem + AB_OFF;        // [112][256] swizzled

  const int tid  = threadIdx.x;
  const int w    = tid >> 6;           // 0..3
  const int lane = tid & 63;
  const int l31  = lane & 31, h32 = lane >> 5;
  const int sw   = (l31 & 7) << 3;     // aB swizzle (per-lane constant)

  // stage X: rows 0..95 -> Xs; rows 96..111 -> linear strip at aB start
  {
    const float4* x4 = (const float4*)(x + (size_t)blockIdx.x * (NODE*NODE));
    for (int i = tid; i < (NODE*NODE/4); i += 256) {
      float4 v = x4[i];
      int r = i / 28, c4 = (i - r*28) * 4;
      uint2 pv; pv.x = pk2(v.x, v.y); pv.y = pk2(v.z, v.w);
      ushort_t* dst = (r < 96) ? (Xs + r*SXS + c4) : (aB + (r-96)*SXS + c4);
      *(uint2*)dst = pv;
    }
  }
  __syncthreads();

  // X rows 96..111 -> registers (lane's clamped row), then free the strip
  bf8v Xr3[7];
  {
    const ushort_t* sp = aB + (l31 & 15)*SXS + h32*8;
    #pragma unroll
    for (int ks=0;ks<7;ks++) Xr3[ks] = ld_frag(sp + ks*16);
  }
  __syncthreads();

  unsigned frA[28], frB[28];

  // phase 1: proj reads only Xs/Xr3 -> no internal barrier; agg cols
  // disjoint per (wave, tile). Tiles {w, w+4}.
  proj1_exch(Xs, Xr3, wsp, b1, w, lane, frA);
  agg_half<0>(frA, Xs, Xr3, aB, w, lane, sw);
  agg_half<2>(frA, Xs, Xr3, aB, w, lane, sw);
  proj1_exch(Xs, Xr3, wsp, b1, w+4, lane, frB);
  agg_half<0>(frB, Xs, Xr3, aB, w+4, lane, sw);
  agg_half<2>(frB, Xs, Xr3, aB, w+4, lane, sw);
  __syncthreads();

  // phase 2: F=256, K=256; both proj tiles read aB fully, then barrier,
  // then both agg tiles write.
  proj_exch<16>(aB, wsp + 28672, 256, b2, w,   lane, sw, frA);
  proj_exch<16>(aB, wsp + 28672, 256, b2, w+4, lane, sw, frB);
  __syncthreads();
  agg_half<0>(frA, Xs, Xr3, aB, w,   lane, sw);
  agg_half<2>(frA, Xs, Xr3, aB, w,   lane, sw);
  agg_half<0>(frB, Xs, Xr3, aB, w+4, lane, sw);
  agg_half<2>(frB, Xs, Xr3, aB, w+4, lane, sw);
  __syncthreads();

  // phase 3: F=128, K=256; tiles 0..3 -> all 4 waves
  proj_exch<16>(aB, wsp + 94208, 256, b3, w, lane, sw, frA);
  __syncthreads();
  agg_half<0>(frA, Xs, Xr3, aB, w, lane, sw);
  agg_half<2>(frA, Xs, Xr3, aB, w, lane, sw);
  __syncthreads();

  // phase 4: F=64, K=128; tiles 0..1 -> waves 0..1
  if (w < 2) proj_exch<8>(aB, wsp + 126976, 128, b4, w, lane, sw, frA);
  __syncthreads();
  if (w < 2) {
    agg_half<0>(frA, Xs, Xr3, aB, w, lane, sw);
    agg_half<2>(frA, Xs, Xr3, aB, w, lane, sw);
  }
  __syncthreads();

  // final: h5[n] = relu(b5 + a5[n][:].W5); out = bf + sum_n h5[n]*Wf[n]
  float partial = 0.f;
  if (tid < NODE) {
    const int swr = (tid & 7) << 3;
    const ushort_t* row = aB + tid*256;
    float s = 0.f;
    #pragma unroll
    for (int k4 = 0; k4 < 16; k4++) {
      uint2 u = *(const uint2*)(row + ((4*k4) ^ swr));
      s += bf2f((ushort_t)(u.x & 0xFFFF)) * W5[k4*4+0];
      s += bf2f((ushort_t)(u.x >> 16))    * W5[k4*4+1];
      s += bf2f((ushort_t)(u.y & 0xFFFF)) * W5[k4*4+2];
      s += bf2f((ushort_t)(u.y >> 16))    * W5[k4*4+3];
    }
    s += b5[0];
    s = s > 0.f ? s : 0.f;
    partial = s * Wf[tid];
  }
  float* red = (float*)Xs;             // Xs dead after phase 4
  if (tid < 128) red[tid] = partial;   // lanes 112..127 write 0
  __syncthreads();
  if (w == 0) {
    float v = red[lane] + red[lane + 64];
    #pragma unroll
    for (int off = 32; off > 0; off >>= 1)
      v += __shfl_xor(v, off, 64);
    if (lane == 0) out[blockIdx.x] = v + bfc[0];
  }
}

extern "C" void kernel_launch(void* const* d_in, const int* in_sizes, int n_in,
                              void* d_out, int out_size, void* d_ws, size_t ws_size,
                              hipStream_t stream) {
  const float* x   = (const float*)d_in[0];
  const float* W1  = (const float*)d_in[1];
  const float* b1  = (const float*)d_in[2];
  const float* W2  = (const float*)d_in[3];
  const float* b2  = (const float*)d_in[4];
  const float* W3  = (const float*)d_in[5];
  const float* b3  = (const float*)d_in[6];
  const float* W4  = (const float*)d_in[7];
  const float* b4  = (const float*)d_in[8];
  const float* W5  = (const float*)d_in[9];
  const float* b5  = (const float*)d_in[10];
  const float* Wf  = (const float*)d_in[11];
  const float* bfc = (const float*)d_in[12];
  ushort_t* wsp = (ushort_t*)d_ws;
  float* out = (float*)d_out;

  prep_weights<<<528, 256, 0, stream>>>(W1, W2, W3, W4, wsp);

  (void)hipFuncSetAttribute((const void*)gcn_kernel,
                            hipFuncAttributeMaxDynamicSharedMemorySize, SMEM_BYTES);
  gcn_kernel<<<NBATCH, 256, SMEM_BYTES, stream>>>(x, wsp, b1, b2, b3, b4,
                                                  W5, b5, Wf, bfc, out);
}